// Round 3
// baseline (54.202 us; speedup 1.0000x reference)
//
#include <hip/hip_runtime.h>

// Packed volume-render (NeRF ray compositing).
// Pass 1: stream ridx (int4), write per-ray segment start offsets into d_ws.
// Pass 2: ONE THREAD PER RAY:
//   - running transmittance T, w_i = T*(1-exp(-tau_i)), T *= exp(-tau_i)
//     (one exp per sample; exactly equals exp(-excl_cumsum)*(1-exp(-tau)))
//   - per-lane float4 loads (peel to 4-sample alignment; i%4==0 makes
//     density/deltas/depths (16i B) and color (12i B) all 16B-aligned)
//   - early exit when T < 1e-5: remaining contribution to every output is
//     bounded by T (colors/depths in [0,1)), far below the 2e-2 threshold.

__global__ __launch_bounds__(256) void starts_kernel(
    const int* __restrict__ ridx, int* __restrict__ starts,
    int n_samples, int n_rays)
{
    const int t = blockIdx.x * blockDim.x + threadIdx.x;
    const int i0 = t * 4;
    if (i0 >= n_samples) return;

    int prev = (i0 == 0) ? -1 : ridx[i0 - 1];
    const int nj = min(4, n_samples - i0);
    if (nj == 4) {
        const int4 v = *reinterpret_cast<const int4*>(ridx + i0);
        const int cur[4] = {v.x, v.y, v.z, v.w};
        #pragma unroll
        for (int j = 0; j < 4; ++j) {
            const int c = cur[j];
            for (int r = prev + 1; r <= c; ++r) starts[r] = i0 + j;
            prev = c;
        }
    } else {
        for (int j = 0; j < nj; ++j) {
            const int c = ridx[i0 + j];
            for (int r = prev + 1; r <= c; ++r) starts[r] = i0 + j;
            prev = c;
        }
    }
    if (i0 + 4 >= n_samples) {       // last thread closes the table
        for (int r = prev + 1; r <= n_rays; ++r) starts[r] = n_samples;
    }
}

__device__ __forceinline__ void sample1(
    float dens, float del, float c0, float c1, float c2, float dp,
    float& T, float& aw, float& ar, float& ag, float& ab, float& ad)
{
    const float tau = dens * del;
    const float e = __expf(-tau);
    const float w = T * (1.0f - e);
    T *= e;
    aw += w;
    ar += w * c0;
    ag += w * c1;
    ab += w * c2;
    ad += w * dp;
}

template <bool USE_STARTS>
__global__ __launch_bounds__(256) void render_kernel(
    const float* __restrict__ color,    // [N,3]
    const float* __restrict__ density,  // [N,1]
    const float* __restrict__ deltas,   // [N,1]
    const float* __restrict__ depths,   // [N,1]
    const int*   __restrict__ ridx,     // [N] sorted (fallback path only)
    const int*   __restrict__ starts,   // [R+1]
    float*       __restrict__ out,      // rgb[3R] | depth[R] | alpha[R] | hit[R]
    int n_samples, int n_rays)
{
    const int r = blockIdx.x * blockDim.x + threadIdx.x;
    if (r >= n_rays) return;

    int i, end;
    if (USE_STARTS) {
        i   = starts[r];
        end = starts[r + 1];
    } else {
        int lo = 0, hi = n_samples;                 // lower_bound(r)
        while (lo < hi) { int m = (lo + hi) >> 1; if (ridx[m] < r) lo = m + 1; else hi = m; }
        i = lo;
        int lo2 = lo; hi = n_samples;               // lower_bound(r+1)
        while (lo2 < hi) { int m = (lo2 + hi) >> 1; if (ridx[m] < r + 1) lo2 = m + 1; else hi = m; }
        end = lo2;
    }

    float T = 1.0f, aw = 0.0f, ar = 0.0f, ag = 0.0f, ab = 0.0f, ad = 0.0f;
    const float TEPS = 1e-5f;

    // scalar peel to 4-sample alignment
    while (i < end && (i & 3) && T > TEPS) {
        sample1(density[i], deltas[i],
                color[3 * i], color[3 * i + 1], color[3 * i + 2], depths[i],
                T, aw, ar, ag, ab, ad);
        ++i;
    }
    // vectorized main loop: 4 samples per iteration, all loads 16B aligned
    for (; i + 4 <= end && T > TEPS; i += 4) {
        const float4 dn = *reinterpret_cast<const float4*>(density + i);
        const float4 dl = *reinterpret_cast<const float4*>(deltas + i);
        const float4 dp = *reinterpret_cast<const float4*>(depths + i);
        const float4* c4 = reinterpret_cast<const float4*>(color + 3 * i);
        const float4 ca = c4[0], cb = c4[1], cc = c4[2];
        sample1(dn.x, dl.x, ca.x, ca.y, ca.z, dp.x, T, aw, ar, ag, ab, ad);
        sample1(dn.y, dl.y, ca.w, cb.x, cb.y, dp.y, T, aw, ar, ag, ab, ad);
        sample1(dn.z, dl.z, cb.z, cb.w, cc.x, dp.z, T, aw, ar, ag, ab, ad);
        sample1(dn.w, dl.w, cc.y, cc.z, cc.w, dp.w, T, aw, ar, ag, ab, ad);
    }
    // scalar tail
    while (i < end && T > TEPS) {
        sample1(density[i], deltas[i],
                color[3 * i], color[3 * i + 1], color[3 * i + 2], depths[i],
                T, aw, ar, ag, ab, ad);
        ++i;
    }

    const float alpha = aw;
    out[3 * r + 0] = (1.0f - alpha) + alpha * ar;   // white background composite
    out[3 * r + 1] = (1.0f - alpha) + alpha * ag;
    out[3 * r + 2] = (1.0f - alpha) + alpha * ab;
    out[3 * n_rays + r] = ad;                       // depth
    out[4 * n_rays + r] = alpha;                    // alpha
    out[5 * n_rays + r] = (alpha > 0.0f) ? 1.0f : 0.0f;  // hit
}

extern "C" void kernel_launch(void* const* d_in, const int* in_sizes, int n_in,
                              void* d_out, int out_size, void* d_ws, size_t ws_size,
                              hipStream_t stream) {
    const float* color   = (const float*)d_in[0];
    const float* density = (const float*)d_in[1];
    const float* deltas  = (const float*)d_in[2];
    const float* depths  = (const float*)d_in[3];
    const int*   ridx    = (const int*)d_in[4];
    float* out = (float*)d_out;

    const int n_samples = in_sizes[1];      // density element count == N
    const int n_rays    = out_size / 6;     // rgb(3R) + depth(R) + alpha(R) + hit(R)

    const size_t starts_bytes = (size_t)(n_rays + 1) * sizeof(int);
    const int rblocks = (n_rays + 255) / 256;

    if (ws_size >= starts_bytes) {
        int* starts = (int*)d_ws;
        const int nthreads = (n_samples + 3) / 4;
        const int sblocks = (nthreads + 255) / 256;
        starts_kernel<<<sblocks, 256, 0, stream>>>(ridx, starts, n_samples, n_rays);
        render_kernel<true><<<rblocks, 256, 0, stream>>>(
            color, density, deltas, depths, ridx, starts, out, n_samples, n_rays);
    } else {
        render_kernel<false><<<rblocks, 256, 0, stream>>>(
            color, density, deltas, depths, ridx, (const int*)nullptr, out,
            n_samples, n_rays);
    }
}